// Round 1
// baseline (193.686 us; speedup 1.0000x reference)
//
#include <hip/hip_runtime.h>
#include <hip/hip_bf16.h>

typedef __attribute__((ext_vector_type(4))) float f32x4;
typedef __attribute__((ext_vector_type(8))) short s16x8;
typedef unsigned int uint;
typedef unsigned short ushort;

// N=8192 nodes, INP=512, OUT=256
// out = relu(D^-1/2 (binA+I) D^-1/2 (x@w)) @ lin_w^T + lin_b

__device__ inline ushort f2bf(float f) {
  union { float f; uint u; } v; v.f = f;
  uint r = (v.u + 0x7FFFu + ((v.u >> 16) & 1u)) >> 16;   // RNE
  return (ushort)r;
}
__device__ inline float bf2f(ushort h) {
  union { uint u; float f; } v; v.u = ((uint)h) << 16;
  return v.f;
}

// ---------------- K1: degrees + bit-pack binarized adj -------------------
// one block per row; thread t covers elements [t*32, t*32+32) -> one uint32 of bits
__global__ __launch_bounds__(256) void k_deg(const float* __restrict__ adj,
                                             uint* __restrict__ bits,
                                             float* __restrict__ dinv) {
  __shared__ int part[4];
  const int row = blockIdx.x;
  const int t = threadIdx.x;
  const float4* src = (const float4*)(adj + (size_t)row * 8192) + (size_t)t * 8;
  uint w = 0u;
#pragma unroll
  for (int i = 0; i < 8; i++) {
    float4 v = src[i];
    uint b = (v.x > 0.5f ? 1u : 0u) | (v.y > 0.5f ? 2u : 0u) |
             (v.z > 0.5f ? 4u : 0u) | (v.w > 0.5f ? 8u : 0u);
    w |= b << (i * 4);
  }
  bits[(size_t)row * 256 + t] = w;
  int c = __popc(w);
#pragma unroll
  for (int o = 32; o > 0; o >>= 1) c += __shfl_down(c, o);
  if ((t & 63) == 0) part[t >> 6] = c;
  __syncthreads();
  if (t == 0) {
    float deg = (float)(part[0] + part[1] + part[2] + part[3] + 1); // +1 self loop
    dinv[row] = rsqrtf(deg);
  }
}

// ---------------- K2: z = d_j * (x @ w), store bf16 row-major AND transposed ---
// grid 256 blocks (32 rows each), 512 threads: thread=(rg 0..7, cg 0..63) -> 4x4 microtile
__global__ __launch_bounds__(512) void k_xw(const float* __restrict__ x,
                                            const float* __restrict__ w,
                                            const float* __restrict__ dinv,
                                            ushort* __restrict__ z,
                                            ushort* __restrict__ zT) {
  __shared__ float xs[32 * 512];  // 64 KB
  const int j0 = blockIdx.x * 32;
  const int t = threadIdx.x;
  {
    const float4* src = (const float4*)(x + (size_t)j0 * 512);
    float4* dst = (float4*)xs;
#pragma unroll
    for (int s = 0; s < 8; s++) dst[t + s * 512] = src[t + s * 512];
  }
  __syncthreads();
  const int rg = t >> 6, cg = t & 63;
  float acc[4][4];
#pragma unroll
  for (int i = 0; i < 4; i++)
#pragma unroll
    for (int j = 0; j < 4; j++) acc[i][j] = 0.f;

  for (int k = 0; k < 512; k += 4) {
    float xe[4][4];
#pragma unroll
    for (int i = 0; i < 4; i++) {
      float4 xv = *(const float4*)&xs[(rg * 4 + i) * 512 + k];
      xe[i][0] = xv.x; xe[i][1] = xv.y; xe[i][2] = xv.z; xe[i][3] = xv.w;
    }
#pragma unroll
    for (int kk = 0; kk < 4; kk++) {
      float4 wv = *(const float4*)(w + (size_t)(k + kk) * 256 + cg * 4);
#pragma unroll
      for (int i = 0; i < 4; i++) {
        acc[i][0] += xe[i][kk] * wv.x;
        acc[i][1] += xe[i][kk] * wv.y;
        acc[i][2] += xe[i][kk] * wv.z;
        acc[i][3] += xe[i][kk] * wv.w;
      }
    }
  }
  ushort zu[4][4];
#pragma unroll
  for (int i = 0; i < 4; i++) {
    float dj = dinv[j0 + rg * 4 + i];
#pragma unroll
    for (int j = 0; j < 4; j++) zu[i][j] = f2bf(dj * acc[i][j]);
  }
#pragma unroll
  for (int i = 0; i < 4; i++) {
    uint2 pk;
    pk.x = (uint)zu[i][0] | ((uint)zu[i][1] << 16);
    pk.y = (uint)zu[i][2] | ((uint)zu[i][3] << 16);
    *(uint2*)&z[(size_t)(j0 + rg * 4 + i) * 256 + cg * 4] = pk;
  }
#pragma unroll
  for (int j = 0; j < 4; j++) {
    uint2 pk;
    pk.x = (uint)zu[0][j] | ((uint)zu[1][j] << 16);
    pk.y = (uint)zu[2][j] | ((uint)zu[3][j] << 16);
    *(uint2*)&zT[(size_t)(cg * 4 + j) * 8192 + j0 + rg * 4] = pk;
  }
}

// ---------------- K3: acc += binA @ z  (bit-unpacked bf16 MFMA, split-K=4) ----
// grid = 64 m-blocks x 4 k-chunks; 512 thr = 8 waves (mg 0..1 x ng 0..3)
// per wave: 64 rows x 64 cols -> 4x4 frags of 16x16, K-step 32
__global__ __launch_bounds__(512) void k_spmm(const uint* __restrict__ bits,
                                              const ushort* __restrict__ zT,
                                              float* __restrict__ accb) {
  __shared__ uint blds[128 * 64];        // 32 KB: bits, dword-XOR-swizzled
  __shared__ ushort ztile[2][256 * 32];  // 2 x 16 KB: z-tile [n][k] granule-swizzled
  const int bx = blockIdx.x;
  const int mb = bx & 63, kc = bx >> 6;
  const int m0 = mb * 128;
  const int t = threadIdx.x;
  const int lane = t & 63, wid = t >> 6;
  const int mg = wid >> 2, ng = wid & 3;

  // stage bits: rows m0..m0+128, 64 dwords (=2048 bits) per row for this k-chunk
  {
    int row = t >> 2, prt = t & 3;
    const uint4* src = (const uint4*)(bits + (size_t)(m0 + row) * 256 + kc * 64 + prt * 16);
    uint4 a = src[0], b = src[1], c = src[2], d = src[3];
    uint vals[16] = {a.x, a.y, a.z, a.w, b.x, b.y, b.z, b.w,
                     c.x, c.y, c.z, c.w, d.x, d.y, d.z, d.w};
    int sw = (row & 15) * 4;
#pragma unroll
    for (int i = 0; i < 16; i++)
      blds[row * 64 + ((prt * 16 + i) ^ sw)] = vals[i];
  }
  // z staging addresses (constant per thread)
  const int zn = t >> 1, zseg = t & 1;
  const ushort* zsrc = zT + (size_t)zn * 8192 + (size_t)kc * 2048 + zseg * 16;
  const int ze0 = zn * 32 + (((zseg * 2 + 0) ^ (zn & 3)) * 8);
  const int ze1 = zn * 32 + (((zseg * 2 + 1) ^ (zn & 3)) * 8);
  {
    uint4 va = *(const uint4*)(zsrc);
    uint4 vb = *(const uint4*)(zsrc + 8);
    *(uint4*)&ztile[0][ze0] = va;
    *(uint4*)&ztile[0][ze1] = vb;
  }
  __syncthreads();

  f32x4 zero4 = {0.f, 0.f, 0.f, 0.f};
  f32x4 acc[4][4];
#pragma unroll
  for (int f = 0; f < 4; f++)
#pragma unroll
    for (int q = 0; q < 4; q++) acc[f][q] = zero4;

  const int rl = lane & 15;
  const int shft = (lane >> 4) * 8;
  const int asw = rl * 4;
  int arow[4], be[4];
#pragma unroll
  for (int f = 0; f < 4; f++) arow[f] = (mg * 64 + f * 16 + rl) * 64;
#pragma unroll
  for (int q = 0; q < 4; q++) {
    int n = ng * 64 + q * 16 + rl;
    be[q] = n * 32 + (((lane >> 4) ^ (n & 3)) * 8);
  }

  for (int ks = 0; ks < 64; ks++) {
    const int cur = ks & 1;
    uint4 va = {0, 0, 0, 0}, vb = {0, 0, 0, 0};
    const bool more = (ks + 1 < 64);
    if (more) {
      va = *(const uint4*)(zsrc + (ks + 1) * 32);
      vb = *(const uint4*)(zsrc + (ks + 1) * 32 + 8);
    }
    uint aw[4];
#pragma unroll
    for (int f = 0; f < 4; f++) aw[f] = blds[arow[f] + (ks ^ asw)];
    union { uint4 u; s16x8 s; } bu[4];
#pragma unroll
    for (int q = 0; q < 4; q++) bu[q].u = *(const uint4*)&ztile[cur][be[q]];
#pragma unroll
    for (int f = 0; f < 4; f++) {
      uint byt = (aw[f] >> shft) & 0xFFu;
      union { uint4 u; s16x8 s; } au;
      au.u.x = ((byt & 1u) ? 0x3F80u : 0u) | ((byt & 2u) ? 0x3F800000u : 0u);
      au.u.y = ((byt & 4u) ? 0x3F80u : 0u) | ((byt & 8u) ? 0x3F800000u : 0u);
      au.u.z = ((byt & 16u) ? 0x3F80u : 0u) | ((byt & 32u) ? 0x3F800000u : 0u);
      au.u.w = ((byt & 64u) ? 0x3F80u : 0u) | ((byt & 128u) ? 0x3F800000u : 0u);
#pragma unroll
      for (int q = 0; q < 4; q++)
        acc[f][q] = __builtin_amdgcn_mfma_f32_16x16x32_bf16(au.s, bu[q].s, acc[f][q], 0, 0, 0);
    }
    if (more) {
      *(uint4*)&ztile[cur ^ 1][ze0] = va;
      *(uint4*)&ztile[cur ^ 1][ze1] = vb;
    }
    __syncthreads();
  }
  // epilogue: atomic accumulate (4 k-chunks per output)
  const int orow0 = m0 + mg * 64;
#pragma unroll
  for (int f = 0; f < 4; f++)
#pragma unroll
    for (int q = 0; q < 4; q++)
#pragma unroll
      for (int r = 0; r < 4; r++) {
        int row = orow0 + f * 16 + (lane >> 4) * 4 + r;
        int col = ng * 64 + q * 16 + rl;
        unsafeAtomicAdd(&accb[(size_t)row * 256 + col], acc[f][q][r]);
      }
}

// ---------------- K4: h = relu(d_i*(acc + z_i)); out = h @ lin_w^T + lin_b ----
// grid 256 blocks (32 rows), 512 thr; reads acc rows from d_out, overwrites them
__global__ __launch_bounds__(512) void k_lin(float* outacc,   // acc in, out overwritten
                                             const ushort* __restrict__ z,
                                             const float* __restrict__ dinv,
                                             const float* __restrict__ lw,
                                             const float* __restrict__ lb) {
  __shared__ float hs[32 * 256];    // 32 KB
  __shared__ float lwT[16 * 260];   // 16.6 KB  lwT[nn][o] = lin_w[o][n0+nn]
  const int i0 = blockIdx.x * 32;
  const int t = threadIdx.x;
#pragma unroll
  for (int s = 0; s < 16; s++) {
    int idx = t + s * 512;
    int r = idx >> 8, c = idx & 255;
    float a = outacc[(size_t)(i0 + r) * 256 + c];
    float zf = bf2f(z[(size_t)(i0 + r) * 256 + c]);
    float h = dinv[i0 + r] * (a + zf);
    hs[idx] = h > 0.f ? h : 0.f;
  }
  const int rg = t >> 6, cg = t & 63;
  const int o = t >> 1, seg = t & 1;
  float s4[4][4];
#pragma unroll
  for (int i = 0; i < 4; i++)
#pragma unroll
    for (int j = 0; j < 4; j++) s4[i][j] = 0.f;

  for (int ch = 0; ch < 16; ch++) {
    const int n0 = ch * 16;
    __syncthreads();  // first iter: also fences hs staging
    {
      float4 p0 = *(const float4*)(lw + (size_t)o * 256 + n0 + seg * 8);
      float4 p1 = *(const float4*)(lw + (size_t)o * 256 + n0 + seg * 8 + 4);
      lwT[(seg * 8 + 0) * 260 + o] = p0.x;
      lwT[(seg * 8 + 1) * 260 + o] = p0.y;
      lwT[(seg * 8 + 2) * 260 + o] = p0.z;
      lwT[(seg * 8 + 3) * 260 + o] = p0.w;
      lwT[(seg * 8 + 4) * 260 + o] = p1.x;
      lwT[(seg * 8 + 5) * 260 + o] = p1.y;
      lwT[(seg * 8 + 6) * 260 + o] = p1.z;
      lwT[(seg * 8 + 7) * 260 + o] = p1.w;
    }
    __syncthreads();
#pragma unroll
    for (int gg = 0; gg < 4; gg++) {
      float he[4][4];
#pragma unroll
      for (int i = 0; i < 4; i++) {
        float4 h4 = *(const float4*)&hs[(rg * 4 + i) * 256 + n0 + gg * 4];
        he[i][0] = h4.x; he[i][1] = h4.y; he[i][2] = h4.z; he[i][3] = h4.w;
      }
#pragma unroll
      for (int kk = 0; kk < 4; kk++) {
        float4 wv = *(const float4*)&lwT[(gg * 4 + kk) * 260 + cg * 4];
#pragma unroll
        for (int i = 0; i < 4; i++) {
          s4[i][0] += he[i][kk] * wv.x;
          s4[i][1] += he[i][kk] * wv.y;
          s4[i][2] += he[i][kk] * wv.z;
          s4[i][3] += he[i][kk] * wv.w;
        }
      }
    }
  }
  float4 bb = *(const float4*)(lb + cg * 4);
#pragma unroll
  for (int i = 0; i < 4; i++) {
    float4 o4;
    o4.x = s4[i][0] + bb.x; o4.y = s4[i][1] + bb.y;
    o4.z = s4[i][2] + bb.z; o4.w = s4[i][3] + bb.w;
    *(float4*)(outacc + (size_t)(i0 + rg * 4 + i) * 256 + cg * 4) = o4;
  }
}

extern "C" void kernel_launch(void* const* d_in, const int* in_sizes, int n_in,
                              void* d_out, int out_size, void* d_ws, size_t ws_size,
                              hipStream_t stream) {
  const float* x   = (const float*)d_in[0];
  const float* adj = (const float*)d_in[1];
  const float* w   = (const float*)d_in[2];
  const float* lw  = (const float*)d_in[3];
  const float* lb  = (const float*)d_in[4];
  float* out = (float*)d_out;

  char* ws = (char*)d_ws;
  float* dinv = (float*)ws;                                   // 32 KB
  uint* bits  = (uint*)(ws + (32u << 10));                    // 8 MB
  ushort* z   = (ushort*)(ws + (32u << 10) + (8u << 20));     // 4 MB
  ushort* zT  = (ushort*)(ws + (32u << 10) + (12u << 20));    // 4 MB

  hipMemsetAsync(d_out, 0, (size_t)out_size * sizeof(float), stream);
  hipLaunchKernelGGL(k_deg, dim3(8192), dim3(256), 0, stream, adj, bits, dinv);
  hipLaunchKernelGGL(k_xw, dim3(256), dim3(512), 0, stream, x, w, dinv, z, zT);
  hipLaunchKernelGGL(k_spmm, dim3(256), dim3(512), 0, stream, bits, zT, out);
  hipLaunchKernelGGL(k_lin, dim3(256), dim3(512), 0, stream, out, z, dinv, lw, lb);
}

// Round 2
// 171.410 us; speedup vs baseline: 1.1300x; 1.1300x over previous
//
#include <hip/hip_runtime.h>
#include <hip/hip_bf16.h>

typedef __attribute__((ext_vector_type(4))) float f32x4;
typedef __attribute__((ext_vector_type(8))) short s16x8;
typedef unsigned int uint;
typedef unsigned short ushort;

// N=8192 nodes, INP=512, OUT=256
// out = relu(D^-1/2 (binA+I) D^-1/2 (x@w)) @ lin_w^T + lin_b
// Associativity: A_hat @ (x@w); binA kept as packed bits, unpacked to bf16 for MFMA.

__device__ inline ushort f2bf(float f) {
  union { float f; uint u; } v; v.f = f;
  uint r = (v.u + 0x7FFFu + ((v.u >> 16) & 1u)) >> 16;   // RNE
  return (ushort)r;
}
__device__ inline float bf2f(ushort h) {
  union { uint u; float f; } v; v.u = ((uint)h) << 16;
  return v.f;
}

// ---------------- K1: degrees + bit-pack binarized adj -------------------
__global__ __launch_bounds__(256) void k_deg(const float* __restrict__ adj,
                                             uint* __restrict__ bits,
                                             float* __restrict__ dinv) {
  __shared__ int part[4];
  const int row = blockIdx.x;
  const int t = threadIdx.x;
  const float4* src = (const float4*)(adj + (size_t)row * 8192) + (size_t)t * 8;
  uint w = 0u;
#pragma unroll
  for (int i = 0; i < 8; i++) {
    float4 v = src[i];
    uint b = (v.x > 0.5f ? 1u : 0u) | (v.y > 0.5f ? 2u : 0u) |
             (v.z > 0.5f ? 4u : 0u) | (v.w > 0.5f ? 8u : 0u);
    w |= b << (i * 4);
  }
  bits[(size_t)row * 256 + t] = w;
  int c = __popc(w);
#pragma unroll
  for (int o = 32; o > 0; o >>= 1) c += __shfl_down(c, o);
  if ((t & 63) == 0) part[t >> 6] = c;
  __syncthreads();
  if (t == 0) {
    float deg = (float)(part[0] + part[1] + part[2] + part[3] + 1); // +1 self loop
    dinv[row] = rsqrtf(deg);
  }
}

// ---------------- K2: z = d_j * (x @ w), store bf16 row-major AND transposed ---
__global__ __launch_bounds__(512) void k_xw(const float* __restrict__ x,
                                            const float* __restrict__ w,
                                            const float* __restrict__ dinv,
                                            ushort* __restrict__ z,
                                            ushort* __restrict__ zT) {
  __shared__ float xs[32 * 512];  // 64 KB
  const int j0 = blockIdx.x * 32;
  const int t = threadIdx.x;
  {
    const float4* src = (const float4*)(x + (size_t)j0 * 512);
    float4* dst = (float4*)xs;
#pragma unroll
    for (int s = 0; s < 8; s++) dst[t + s * 512] = src[t + s * 512];
  }
  __syncthreads();
  const int rg = t >> 6, cg = t & 63;
  float acc[4][4];
#pragma unroll
  for (int i = 0; i < 4; i++)
#pragma unroll
    for (int j = 0; j < 4; j++) acc[i][j] = 0.f;

  for (int k = 0; k < 512; k += 4) {
    float xe[4][4];
#pragma unroll
    for (int i = 0; i < 4; i++) {
      float4 xv = *(const float4*)&xs[(rg * 4 + i) * 512 + k];
      xe[i][0] = xv.x; xe[i][1] = xv.y; xe[i][2] = xv.z; xe[i][3] = xv.w;
    }
#pragma unroll
    for (int kk = 0; kk < 4; kk++) {
      float4 wv = *(const float4*)(w + (size_t)(k + kk) * 256 + cg * 4);
#pragma unroll
      for (int i = 0; i < 4; i++) {
        acc[i][0] += xe[i][kk] * wv.x;
        acc[i][1] += xe[i][kk] * wv.y;
        acc[i][2] += xe[i][kk] * wv.z;
        acc[i][3] += xe[i][kk] * wv.w;
      }
    }
  }
  ushort zu[4][4];
#pragma unroll
  for (int i = 0; i < 4; i++) {
    float dj = dinv[j0 + rg * 4 + i];
#pragma unroll
    for (int j = 0; j < 4; j++) zu[i][j] = f2bf(dj * acc[i][j]);
  }
#pragma unroll
  for (int i = 0; i < 4; i++) {
    uint2 pk;
    pk.x = (uint)zu[i][0] | ((uint)zu[i][1] << 16);
    pk.y = (uint)zu[i][2] | ((uint)zu[i][3] << 16);
    *(uint2*)&z[(size_t)(j0 + rg * 4 + i) * 256 + cg * 4] = pk;
  }
#pragma unroll
  for (int j = 0; j < 4; j++) {
    uint2 pk;
    pk.x = (uint)zu[0][j] | ((uint)zu[1][j] << 16);
    pk.y = (uint)zu[2][j] | ((uint)zu[3][j] << 16);
    *(uint2*)&zT[(size_t)(cg * 4 + j) * 8192 + j0 + rg * 4] = pk;
  }
}

// ---------------- K3: part[kc] = binA[:, kc-chunk] @ z[kc-chunk]  ------------
// grid 256 = 64 mb x 4 kc (kc = bx&3 -> one 1MB zT chunk per XCD L2).
// 8 waves = (kh 0..1) x (ng 0..3); wave tile 128 rows x 64 cols, K-half 1024.
// bits in LDS (swizzled, staged once); B-frags read direct from L2 w/ prefetch.
// No syncthreads in K-loop. kh halves reduced via LDS at the end.
__global__ __launch_bounds__(512, 2) void k_spmm(const uint* __restrict__ bits,
                                                 const ushort* __restrict__ zT,
                                                 float* __restrict__ part) {
  __shared__ uint blds[128 * 64];        // 32 KB
  __shared__ float red[2 * 128 * 68];    // 69.6 KB, padded stride 68
  const int bx = blockIdx.x;
  const int mb = bx >> 2, kc = bx & 3;
  const int m0 = mb * 128;
  const int t = threadIdx.x;
  const int lane = t & 63, wid = t >> 6;
  const int kh = wid >> 2, ng = wid & 3;
  const int rl = lane & 15, kg = lane >> 4;

  // stage bits: rows m0..m0+128, 64 dwords per row for this kc chunk (XOR-swizzled)
  {
    int row = t >> 2, prt = t & 3;
    const uint4* src = (const uint4*)(bits + (size_t)(m0 + row) * 256 + kc * 64 + prt * 16);
    uint4 a = src[0], b = src[1], c = src[2], d = src[3];
    uint vals[16] = {a.x, a.y, a.z, a.w, b.x, b.y, b.z, b.w,
                     c.x, c.y, c.z, c.w, d.x, d.y, d.z, d.w};
    int sw = (row & 15) * 4;
#pragma unroll
    for (int i = 0; i < 16; i++)
      blds[row * 64 + ((prt * 16 + i) ^ sw)] = vals[i];
  }

  // B-fragment source pointers (L2-resident zT[n][k], n-major stride 8192)
  const ushort* zsrc[4];
#pragma unroll
  for (int q = 0; q < 4; q++)
    zsrc[q] = zT + (size_t)(ng * 64 + q * 16 + rl) * 8192 + kc * 2048 + kh * 1024 + kg * 8;

  __syncthreads();  // bits staged

  uint4 bcur[4], bnxt[4];
#pragma unroll
  for (int q = 0; q < 4; q++) bcur[q] = *(const uint4*)(zsrc[q]);

  f32x4 zero4 = {0.f, 0.f, 0.f, 0.f};
  f32x4 acc[8][4];
#pragma unroll
  for (int f = 0; f < 8; f++)
#pragma unroll
    for (int q = 0; q < 4; q++) acc[f][q] = zero4;

  int arow[8];
#pragma unroll
  for (int f = 0; f < 8; f++) arow[f] = (f * 16 + rl) * 64;
  const int asw = rl * 4;
  const int shft = kg * 8;
  const int kcol0 = kh * 32;

  for (int ks = 0; ks < 32; ks++) {
    if (ks + 1 < 32) {
#pragma unroll
      for (int q = 0; q < 4; q++)
        bnxt[q] = *(const uint4*)(zsrc[q] + (size_t)(ks + 1) * 32);
    }
    uint aw[8];
#pragma unroll
    for (int f = 0; f < 8; f++) aw[f] = blds[arow[f] + ((kcol0 + ks) ^ asw)];
#pragma unroll
    for (int f = 0; f < 8; f++) {
      uint byt = (aw[f] >> shft) & 0xFFu;
      union { uint4 u; s16x8 s; } au;
      au.u.x = ((byt & 1u) ? 0x3F80u : 0u) | ((byt & 2u) ? 0x3F800000u : 0u);
      au.u.y = ((byt & 4u) ? 0x3F80u : 0u) | ((byt & 8u) ? 0x3F800000u : 0u);
      au.u.z = ((byt & 16u) ? 0x3F80u : 0u) | ((byt & 32u) ? 0x3F800000u : 0u);
      au.u.w = ((byt & 64u) ? 0x3F80u : 0u) | ((byt & 128u) ? 0x3F800000u : 0u);
#pragma unroll
      for (int q = 0; q < 4; q++) {
        union { uint4 u; s16x8 s; } bu; bu.u = bcur[q];
        acc[f][q] = __builtin_amdgcn_mfma_f32_16x16x32_bf16(au.s, bu.s, acc[f][q], 0, 0, 0);
      }
    }
#pragma unroll
    for (int q = 0; q < 4; q++) bcur[q] = bnxt[q];
  }

  // reduce kh=1 into kh=0 via LDS (2 rounds of 2 ng each), then store partials
#pragma unroll
  for (int half = 0; half < 2; half++) {
    __syncthreads();
    if (kh == 1 && (ng >> 1) == half) {
      const int ngl = ng & 1;
#pragma unroll
      for (int f = 0; f < 8; f++)
#pragma unroll
        for (int q = 0; q < 4; q++)
#pragma unroll
          for (int r = 0; r < 4; r++)
            red[ngl * 8704 + (f * 16 + kg * 4 + r) * 68 + q * 16 + rl] = acc[f][q][r];
    }
    __syncthreads();
    if (kh == 0 && (ng >> 1) == half) {
      const int ngl = ng & 1;
#pragma unroll
      for (int f = 0; f < 8; f++)
#pragma unroll
        for (int q = 0; q < 4; q++)
#pragma unroll
          for (int r = 0; r < 4; r++) {
            int row = f * 16 + kg * 4 + r;
            float v = acc[f][q][r] + red[ngl * 8704 + row * 68 + q * 16 + rl];
            part[((size_t)kc << 21) + (size_t)(m0 + row) * 256 + ng * 64 + q * 16 + rl] = v;
          }
    }
  }
}

// ---------------- K4: h = relu(d_i*(sum(part) + z_i)); out = h @ lin_w^T + lin_b
__global__ __launch_bounds__(512) void k_lin(const float* __restrict__ part,
                                             const ushort* __restrict__ z,
                                             const float* __restrict__ dinv,
                                             const float* __restrict__ lw,
                                             const float* __restrict__ lb,
                                             float* __restrict__ out) {
  __shared__ float hs[32 * 256];    // 32 KB
  __shared__ float lwT[16 * 260];   // 16.6 KB  lwT[nn][o] = lin_w[o][n0+nn]
  const int i0 = blockIdx.x * 32;
  const int t = threadIdx.x;
#pragma unroll
  for (int s = 0; s < 16; s++) {
    int idx = t + s * 512;
    int r = idx >> 8, c = idx & 255;
    size_t g = (size_t)(i0 + r) * 256 + c;
    float a = part[g] + part[g + (1ull << 21)] + part[g + (2ull << 21)] + part[g + (3ull << 21)];
    float h = dinv[i0 + r] * (a + bf2f(z[g]));
    hs[idx] = h > 0.f ? h : 0.f;
  }
  const int rg = t >> 6, cg = t & 63;
  const int o = t >> 1, seg = t & 1;
  float s4[4][4];
#pragma unroll
  for (int i = 0; i < 4; i++)
#pragma unroll
    for (int j = 0; j < 4; j++) s4[i][j] = 0.f;

  for (int ch = 0; ch < 16; ch++) {
    const int n0 = ch * 16;
    __syncthreads();  // first iter: also fences hs staging
    {
      float4 p0 = *(const float4*)(lw + (size_t)o * 256 + n0 + seg * 8);
      float4 p1 = *(const float4*)(lw + (size_t)o * 256 + n0 + seg * 8 + 4);
      lwT[(seg * 8 + 0) * 260 + o] = p0.x;
      lwT[(seg * 8 + 1) * 260 + o] = p0.y;
      lwT[(seg * 8 + 2) * 260 + o] = p0.z;
      lwT[(seg * 8 + 3) * 260 + o] = p0.w;
      lwT[(seg * 8 + 4) * 260 + o] = p1.x;
      lwT[(seg * 8 + 5) * 260 + o] = p1.y;
      lwT[(seg * 8 + 6) * 260 + o] = p1.z;
      lwT[(seg * 8 + 7) * 260 + o] = p1.w;
    }
    __syncthreads();
#pragma unroll
    for (int gg = 0; gg < 4; gg++) {
      float he[4][4];
#pragma unroll
      for (int i = 0; i < 4; i++) {
        float4 h4 = *(const float4*)&hs[(rg * 4 + i) * 256 + n0 + gg * 4];
        he[i][0] = h4.x; he[i][1] = h4.y; he[i][2] = h4.z; he[i][3] = h4.w;
      }
#pragma unroll
      for (int kk = 0; kk < 4; kk++) {
        float4 wv = *(const float4*)&lwT[(gg * 4 + kk) * 260 + cg * 4];
#pragma unroll
        for (int i = 0; i < 4; i++) {
          s4[i][0] += he[i][kk] * wv.x;
          s4[i][1] += he[i][kk] * wv.y;
          s4[i][2] += he[i][kk] * wv.z;
          s4[i][3] += he[i][kk] * wv.w;
        }
      }
    }
  }
  float4 bb = *(const float4*)(lb + cg * 4);
#pragma unroll
  for (int i = 0; i < 4; i++) {
    float4 o4;
    o4.x = s4[i][0] + bb.x; o4.y = s4[i][1] + bb.y;
    o4.z = s4[i][2] + bb.z; o4.w = s4[i][3] + bb.w;
    *(float4*)(out + (size_t)(i0 + rg * 4 + i) * 256 + cg * 4) = o4;
  }
}

extern "C" void kernel_launch(void* const* d_in, const int* in_sizes, int n_in,
                              void* d_out, int out_size, void* d_ws, size_t ws_size,
                              hipStream_t stream) {
  const float* x   = (const float*)d_in[0];
  const float* adj = (const float*)d_in[1];
  const float* w   = (const float*)d_in[2];
  const float* lw  = (const float*)d_in[3];
  const float* lb  = (const float*)d_in[4];
  float* out = (float*)d_out;

  char* ws = (char*)d_ws;
  float* dinv   = (float*)ws;                                    // 32 KB
  uint* bits    = (uint*)(ws + (32u << 10));                     // 8 MB
  ushort* z     = (ushort*)(ws + (32u << 10) + (8u << 20));      // 4 MB
  ushort* zT    = (ushort*)(ws + (32u << 10) + (12u << 20));     // 4 MB
  float* part   = (float*)(ws + (32u << 10) + (16u << 20));      // 32 MB (4 x 8 MB)

  hipLaunchKernelGGL(k_deg, dim3(8192), dim3(256), 0, stream, adj, bits, dinv);
  hipLaunchKernelGGL(k_xw, dim3(256), dim3(512), 0, stream, x, w, dinv, z, zT);
  hipLaunchKernelGGL(k_spmm, dim3(256), dim3(512), 0, stream, bits, zT, part);
  hipLaunchKernelGGL(k_lin, dim3(256), dim3(512), 0, stream, part, z, dinv, lw, lb, out);
}

// Round 3
// 163.323 us; speedup vs baseline: 1.1859x; 1.0495x over previous
//
#include <hip/hip_runtime.h>
#include <hip/hip_bf16.h>

typedef __attribute__((ext_vector_type(4))) float f32x4;
typedef __attribute__((ext_vector_type(8))) short s16x8;
typedef unsigned int uint;
typedef unsigned short ushort;

// N=8192, INP=512, OUT=256
// out = relu(D^-1/2 (binA+I) D^-1/2 (x@w)) @ lin_w^T + lin_b
// binA as packed bits; all GEMMs via bf16 MFMA 16x16x32.

__device__ inline ushort f2bf(float f) {
  union { float f; uint u; } v; v.f = f;
  uint r = (v.u + 0x7FFFu + ((v.u >> 16) & 1u)) >> 16;   // RNE
  return (ushort)r;
}
__device__ inline float bf2f_lo(uint u) { union { uint u; float f; } v; v.u = u << 16; return v.f; }
__device__ inline float bf2f_hi(uint u) { union { uint u; float f; } v; v.u = u & 0xFFFF0000u; return v.f; }
__device__ inline uint pack2(float a, float b) { return (uint)f2bf(a) | ((uint)f2bf(b) << 16); }

// ---------------- K1: degrees + bitpack adj; blocks 0..47 also prep wT/lwb ----
__global__ __launch_bounds__(256) void k_deg(const float* __restrict__ adj,
                                             const float* __restrict__ w,
                                             const float* __restrict__ lw,
                                             uint* __restrict__ bits,
                                             float* __restrict__ dinv,
                                             ushort* __restrict__ wT,
                                             ushort* __restrict__ lwb) {
  __shared__ int psum[4];
  const int row = blockIdx.x;
  const int t = threadIdx.x;
  const float4* src = (const float4*)(adj + (size_t)row * 8192) + t * 8;
  uint wv = 0u;
#pragma unroll
  for (int i = 0; i < 8; i++) {
    float4 v = src[i];
    uint b = (v.x > 0.5f ? 1u : 0u) | (v.y > 0.5f ? 2u : 0u) |
             (v.z > 0.5f ? 4u : 0u) | (v.w > 0.5f ? 8u : 0u);
    wv |= b << (i * 4);
  }
  bits[(size_t)row * 256 + t] = wv;
  int c = __popc(wv);
#pragma unroll
  for (int o = 32; o > 0; o >>= 1) c += __shfl_down(c, o);
  if ((t & 63) == 0) psum[t >> 6] = c;
  __syncthreads();
  if (t == 0) dinv[row] = rsqrtf((float)(psum[0] + psum[1] + psum[2] + psum[3] + 1));
  // prep: wT[n][k] bf16 (blocks 0..31), lwb bf16 copy of lin_w (blocks 32..47)
  if (row < 32) {
#pragma unroll
    for (int rr = 0; rr < 16; rr++) {
      int r = row * 16 + rr;
      wT[t * 512 + r] = f2bf(w[r * 256 + t]);
    }
  } else if (row < 48) {
    int b = row - 32;
#pragma unroll
    for (int i = 0; i < 4; i++) {
      float4 v = ((const float4*)lw)[b * 1024 + i * 256 + t];
      uint2 p; p.x = pack2(v.x, v.y); p.y = pack2(v.z, v.w);
      ((uint2*)lwb)[b * 1024 + i * 256 + t] = p;
    }
  }
}

// ---------------- K2: zT[n][m] = d_m * (x @ w)[m][n], bf16 MFMA ---------------
// grid 256 (m-tile 32), 512 thr = 8 waves (2 mg x 4 ng), wave 16m x 64n
__global__ __launch_bounds__(512) void k_xw(const float* __restrict__ x,
                                            const ushort* __restrict__ wT,
                                            const float* __restrict__ dinv,
                                            ushort* __restrict__ zT) {
  __shared__ ushort xa[32 * 64];   // 4KB, byte layout row*128 + (k*2 ^ ((row&7)<<4))
  __shared__ float sdinv[32];
  const int m0 = blockIdx.x * 32;
  const int t = threadIdx.x;
  const int lane = t & 63, wid = t >> 6;
  const int mg = wid >> 2, ng = wid & 3;
  const int rl = lane & 15, kg = lane >> 4;
  if (t < 32) sdinv[t] = dinv[m0 + t];

  const int srow = t >> 4, sseg = t & 15;
  const float4* xsrc = (const float4*)(x + (size_t)(m0 + srow) * 512) + sseg;
  const int swb = (sseg * 8) ^ ((srow & 7) << 4);
  const int arow = mg * 16 + rl;

  f32x4 acc[4];
#pragma unroll
  for (int q = 0; q < 4; q++) acc[q] = (f32x4){0.f, 0.f, 0.f, 0.f};

  for (int kc = 0; kc < 8; kc++) {
    __syncthreads();
    float4 xv = xsrc[kc * 16];
    uint2 pk; pk.x = pack2(xv.x, xv.y); pk.y = pack2(xv.z, xv.w);
    *(uint2*)((char*)xa + srow * 128 + swb) = pk;
    __syncthreads();
#pragma unroll
    for (int ks = 0; ks < 2; ks++) {
      union { uint4 u; s16x8 s; } av;
      av.u = *(uint4*)((char*)xa + arow * 128 + ((ks * 64 + kg * 16) ^ ((rl & 7) << 4)));
#pragma unroll
      for (int q = 0; q < 4; q++) {
        int n = ng * 64 + q * 16 + rl;
        union { uint4 u; s16x8 s; } bv;
        bv.u = *(const uint4*)(wT + (size_t)n * 512 + kc * 64 + ks * 32 + kg * 8);
        acc[q] = __builtin_amdgcn_mfma_f32_16x16x32_bf16(av.s, bv.s, acc[q], 0, 0, 0);
      }
    }
  }
  const int mb = mg * 16 + kg * 4;
#pragma unroll
  for (int q = 0; q < 4; q++) {
    int n = ng * 64 + q * 16 + rl;
    uint2 p;
    p.x = pack2(acc[q][0] * sdinv[mb], acc[q][1] * sdinv[mb + 1]);
    p.y = pack2(acc[q][2] * sdinv[mb + 2], acc[q][3] * sdinv[mb + 3]);
    *(uint2*)(zT + (size_t)n * 8192 + m0 + mb) = p;
  }
}

// ---------------- K3: part[kc][n][m] = (binA[:,kc] @ z[kc])^T, bf16 ----------
// grid 256 = 32 mb x 8 kc (kc=bx&7 -> XCD-local zT chunk). 8 waves (4 mg x 2 ng),
// wave 64m x 128n, K-chunk 1024 (32 iters). bits LDS-swizzled; B direct L2+prefetch.
__global__ __launch_bounds__(512) void k_spmm(const uint* __restrict__ bits,
                                              const ushort* __restrict__ zT,
                                              ushort* __restrict__ part) {
  __shared__ uint blds[256 * 32];  // 32KB
  const int bx = blockIdx.x;
  const int kc = bx & 7, mb = bx >> 3;
  const int m0 = mb * 256;
  const int t = threadIdx.x;
  const int lane = t & 63, wid = t >> 6;
  const int mg = wid >> 1, ng = wid & 1;
  const int rl = lane & 15, kg = lane >> 4;
  {
    const int row = t >> 1, half = t & 1;
    const uint4* src = (const uint4*)(bits + (size_t)(m0 + row) * 256 + kc * 32 + half * 16);
    uint4 a = src[0], b = src[1], c = src[2], d = src[3];
    uint vals[16] = {a.x, a.y, a.z, a.w, b.x, b.y, b.z, b.w,
                     c.x, c.y, c.z, c.w, d.x, d.y, d.z, d.w};
    const int xr = (row & 15) * 2;
#pragma unroll
    for (int i = 0; i < 16; i++)
      blds[row * 32 + ((half * 16 + i) ^ xr)] = vals[i];
  }
  const ushort* zsrc[8];
#pragma unroll
  for (int q = 0; q < 8; q++)
    zsrc[q] = zT + (size_t)(ng * 128 + q * 16 + rl) * 8192 + kc * 1024 + kg * 8;
  __syncthreads();

  uint4 bcur[8], bnxt[8];
#pragma unroll
  for (int q = 0; q < 8; q++) bcur[q] = *(const uint4*)zsrc[q];

  f32x4 acc[4][8];
#pragma unroll
  for (int f = 0; f < 4; f++)
#pragma unroll
    for (int q = 0; q < 8; q++) acc[f][q] = (f32x4){0.f, 0.f, 0.f, 0.f};

  int arow[4];
#pragma unroll
  for (int f = 0; f < 4; f++) arow[f] = (mg * 64 + f * 16 + rl) * 32;
  const int axor = rl * 2;
  const uint shft = kg * 8;

  for (int ks = 0; ks < 32; ks++) {
    if (ks < 31) {
#pragma unroll
      for (int q = 0; q < 8; q++) bnxt[q] = *(const uint4*)(zsrc[q] + (ks + 1) * 32);
    }
    uint aw[4];
#pragma unroll
    for (int f = 0; f < 4; f++) aw[f] = blds[arow[f] + (ks ^ axor)];
#pragma unroll
    for (int f = 0; f < 4; f++) {
      uint byt = (aw[f] >> shft) & 0xFFu;
      union { uint4 u; s16x8 s; } au;
      au.u.x = ((byt * 0x8001u) & 0x10001u) * 0x3F80u;           // bits 0,1 -> bf16 pair
      au.u.y = (((byt >> 2) * 0x8001u) & 0x10001u) * 0x3F80u;    // bits 2,3
      au.u.z = (((byt >> 4) * 0x8001u) & 0x10001u) * 0x3F80u;    // bits 4,5
      au.u.w = (((byt >> 6) * 0x8001u) & 0x10001u) * 0x3F80u;    // bits 6,7
#pragma unroll
      for (int q = 0; q < 8; q++) {
        union { uint4 u; s16x8 s; } bu; bu.u = bcur[q];
        acc[f][q] = __builtin_amdgcn_mfma_f32_16x16x32_bf16(au.s, bu.s, acc[f][q], 0, 0, 0);
      }
    }
#pragma unroll
    for (int q = 0; q < 8; q++) bcur[q] = bnxt[q];
  }
  ushort* pbase = part + (size_t)kc * 2097152;
#pragma unroll
  for (int f = 0; f < 4; f++)
#pragma unroll
    for (int q = 0; q < 8; q++) {
      int n = ng * 128 + q * 16 + rl;
      int mm = m0 + mg * 64 + f * 16 + kg * 4;
      uint2 p;
      p.x = pack2(acc[f][q][0], acc[f][q][1]);
      p.y = pack2(acc[f][q][2], acc[f][q][3]);
      *(uint2*)(pbase + (size_t)n * 8192 + mm) = p;
    }
}

// ---------------- K4: h = relu(d_m*(sum part + zT)); out = h @ lwb^T + lb ----
// grid 256 (m-tile 32), 512 thr; stage sums -> hA bf16 (swizzled) -> MFMA
__global__ __launch_bounds__(512) void k_lin(const ushort* __restrict__ part,
                                             const ushort* __restrict__ zT,
                                             const float* __restrict__ dinv,
                                             const ushort* __restrict__ lwb,
                                             const float* __restrict__ lb,
                                             float* __restrict__ out) {
  __shared__ ushort hA[32 * 256];  // 16KB, byte layout m*512 + (n*2 ^ ((m&7)<<4))
  __shared__ float sdinv[32];
  const int m0 = blockIdx.x * 32;
  const int t = threadIdx.x;
  if (t < 32) sdinv[t] = dinv[m0 + t];
  {
    const int n = t >> 1, mh = t & 1;
    const ushort* zp = zT + (size_t)n * 8192 + m0 + mh * 16;
    uint4 za = *(const uint4*)zp, zb = *(const uint4*)(zp + 8);
    uint zu[8] = {za.x, za.y, za.z, za.w, zb.x, zb.y, zb.z, zb.w};
    float sum[16];
#pragma unroll
    for (int i = 0; i < 8; i++) { sum[2 * i] = bf2f_lo(zu[i]); sum[2 * i + 1] = bf2f_hi(zu[i]); }
#pragma unroll
    for (int kcp = 0; kcp < 8; kcp++) {
      const ushort* pp = part + (size_t)kcp * 2097152 + (size_t)n * 8192 + m0 + mh * 16;
      uint4 pa = *(const uint4*)pp, pb = *(const uint4*)(pp + 8);
      uint pu[8] = {pa.x, pa.y, pa.z, pa.w, pb.x, pb.y, pb.z, pb.w};
#pragma unroll
      for (int i = 0; i < 8; i++) { sum[2 * i] += bf2f_lo(pu[i]); sum[2 * i + 1] += bf2f_hi(pu[i]); }
    }
    __syncthreads();   // sdinv visible
#pragma unroll
    for (int j = 0; j < 16; j++) {
      int m = mh * 16 + j;
      float h = sum[j] * sdinv[m];
      h = h > 0.f ? h : 0.f;
      *(ushort*)((char*)hA + m * 512 + ((n * 2) ^ ((m & 7) << 4))) = f2bf(h);
    }
  }
  __syncthreads();
  const int lane = t & 63, wid = t >> 6;
  const int rl = lane & 15, kg = lane >> 4;
  f32x4 acc[2][2];
#pragma unroll
  for (int f = 0; f < 2; f++)
#pragma unroll
    for (int q = 0; q < 2; q++) acc[f][q] = (f32x4){0.f, 0.f, 0.f, 0.f};

#pragma unroll
  for (int ks = 0; ks < 8; ks++) {
    union { uint4 u; s16x8 s; } av[2];
#pragma unroll
    for (int f = 0; f < 2; f++)
      av[f].u = *(uint4*)((char*)hA + (f * 16 + rl) * 512 + ((ks * 64 + kg * 16) ^ ((rl & 7) << 4)));
#pragma unroll
    for (int q = 0; q < 2; q++) {
      int no = wid * 32 + q * 16 + rl;
      union { uint4 u; s16x8 s; } bv;
      bv.u = *(const uint4*)(lwb + (size_t)no * 256 + ks * 32 + kg * 8);
#pragma unroll
      for (int f = 0; f < 2; f++)
        acc[f][q] = __builtin_amdgcn_mfma_f32_16x16x32_bf16(av[f].s, bv.s, acc[f][q], 0, 0, 0);
    }
  }
#pragma unroll
  for (int q = 0; q < 2; q++) {
    int no = wid * 32 + q * 16 + rl;
    float bb = lb[no];
#pragma unroll
    for (int f = 0; f < 2; f++) {
      int mbase = m0 + f * 16 + kg * 4;
#pragma unroll
      for (int r = 0; r < 4; r++)
        out[(size_t)(mbase + r) * 256 + no] = acc[f][q][r] + bb;
    }
  }
}

extern "C" void kernel_launch(void* const* d_in, const int* in_sizes, int n_in,
                              void* d_out, int out_size, void* d_ws, size_t ws_size,
                              hipStream_t stream) {
  const float* x   = (const float*)d_in[0];
  const float* adj = (const float*)d_in[1];
  const float* w   = (const float*)d_in[2];
  const float* lw  = (const float*)d_in[3];
  const float* lb  = (const float*)d_in[4];
  float* out = (float*)d_out;

  char* ws = (char*)d_ws;
  float*  dinv = (float*)(ws + 0);                 // 32KB
  uint*   bits = (uint*)(ws + (1ull << 20));       // 8MB
  ushort* zT   = (ushort*)(ws + (9ull << 20));     // 4MB   [256 n][8192 m]
  ushort* wT   = (ushort*)(ws + (13ull << 20));    // 256KB [256 n][512 k]
  ushort* lwb  = (ushort*)(ws + (14ull << 20));    // 128KB [256 o][256 k]
  ushort* part = (ushort*)(ws + (16ull << 20));    // 32MB  [8 kc][256 n][8192 m]

  hipLaunchKernelGGL(k_deg, dim3(8192), dim3(256), 0, stream, adj, w, lw, bits, dinv, wT, lwb);
  hipLaunchKernelGGL(k_xw, dim3(256), dim3(512), 0, stream, x, wT, dinv, zT);
  hipLaunchKernelGGL(k_spmm, dim3(256), dim3(512), 0, stream, bits, zT, part);
  hipLaunchKernelGGL(k_lin, dim3(256), dim3(512), 0, stream, part, zT, dinv, lwb, lb, out);
}